// Round 1
// baseline (598.402 us; speedup 1.0000x reference)
//
#include <hip/hip_runtime.h>
#include <stdint.h>

// Problem constants (from reference): B=32 batch, K=1024 capsules, C=64 classes,
// O=32 out dim, I=32 in dim, 3 routing iterations.
#define Bb 32
#define Kk 1024
#define Cc 64
#define Oo 32
#define Ii 32

typedef __attribute__((ext_vector_type(8))) short bf16x8;
typedef __attribute__((ext_vector_type(4))) float f32x4;

__device__ __forceinline__ short f2bf(float f) {
    uint32_t u = __builtin_bit_cast(uint32_t, f);
    u += 0x7fffu + ((u >> 16) & 1u);   // round-to-nearest-even (no NaN inputs here)
    return (short)(u >> 16);
}
__device__ __forceinline__ float bflo(uint32_t u) { return __builtin_bit_cast(float, u << 16); }
__device__ __forceinline__ float bfhi(uint32_t u) { return __builtin_bit_cast(float, u & 0xffff0000u); }
__device__ __forceinline__ uint32_t pk2(float a, float b) {
    return (uint32_t)(uint16_t)f2bf(a) | ((uint32_t)(uint16_t)f2bf(b) << 16);
}

// u_hat storage: per (k,c), 1024 bf16 values laid out as [lane][t][r]:
//   element (t,r) of lane l is u_hat[b][o] with b=(t&1)*16+(l&15),
//   o=(t>>1)*16+(l>>4)*4+r  (the mfma_f32_16x16x32 C/D mapping, m89-verified).
// Each lane owns 16 contiguous bf16 = 32 B -> 2x dwordx4, fully coalesced.

// K1: u_hat[o,b] = sum_i W[k,c,o,i] * x[b,k,i] via MFMA, per-block one k, all c.
__global__ __launch_bounds__(256) void k_uhat(const float* __restrict__ x,
                                              const float* __restrict__ W,
                                              uint16_t* __restrict__ uh) {
    const int k = blockIdx.x;
    const int lane = threadIdx.x & 63;
    const int wave = threadIdx.x >> 6;
    const int m = lane & 15;
    const int q = lane >> 4;

    // B operand: B[kk=i][n=b_local] = x[b0+n, k, i]; lane holds 8 consecutive i.
    bf16x8 bfrag[2];
#pragma unroll
    for (int nb = 0; nb < 2; ++nb) {
        const float* xp = x + (size_t)((nb * 16 + m) * Kk + k) * Ii + q * 8;
        f32x4 a = *(const f32x4*)xp;
        f32x4 b = *(const f32x4*)(xp + 4);
        bf16x8 t;
        t[0] = f2bf(a.x); t[1] = f2bf(a.y); t[2] = f2bf(a.z); t[3] = f2bf(a.w);
        t[4] = f2bf(b.x); t[5] = f2bf(b.y); t[6] = f2bf(b.z); t[7] = f2bf(b.w);
        bfrag[nb] = t;
    }

    for (int cc = 0; cc < 16; ++cc) {
        const int c = wave * 16 + cc;
        // A operand: A[m=o_local][kk=i] = W[k,c,o0+m,i]; native row-major W works.
        bf16x8 afrag[2];
#pragma unroll
        for (int mo = 0; mo < 2; ++mo) {
            const float* wp = W + (size_t)((k * Cc + c) * Oo + mo * 16 + m) * Ii + q * 8;
            f32x4 a = *(const f32x4*)wp;
            f32x4 b = *(const f32x4*)(wp + 4);
            bf16x8 t;
            t[0] = f2bf(a.x); t[1] = f2bf(a.y); t[2] = f2bf(a.z); t[3] = f2bf(a.w);
            t[4] = f2bf(b.x); t[5] = f2bf(b.y); t[6] = f2bf(b.z); t[7] = f2bf(b.w);
            afrag[mo] = t;
        }
        const f32x4 z = {0.f, 0.f, 0.f, 0.f};
        f32x4 d0 = __builtin_amdgcn_mfma_f32_16x16x32_bf16(afrag[0], bfrag[0], z, 0, 0, 0);
        f32x4 d1 = __builtin_amdgcn_mfma_f32_16x16x32_bf16(afrag[0], bfrag[1], z, 0, 0, 0);
        f32x4 d2 = __builtin_amdgcn_mfma_f32_16x16x32_bf16(afrag[1], bfrag[0], z, 0, 0, 0);
        f32x4 d3 = __builtin_amdgcn_mfma_f32_16x16x32_bf16(afrag[1], bfrag[1], z, 0, 0, 0);

        uint4 p0, p1;
        p0.x = pk2(d0.x, d0.y); p0.y = pk2(d0.z, d0.w);
        p0.z = pk2(d1.x, d1.y); p0.w = pk2(d1.z, d1.w);
        p1.x = pk2(d2.x, d2.y); p1.y = pk2(d2.z, d2.w);
        p1.z = pk2(d3.x, d3.y); p1.w = pk2(d3.z, d3.w);
        uint16_t* dst = uh + ((size_t)(k * Cc + c) * 64 + lane) * 16;
        *(uint4*)dst = p0;
        *(uint4*)(dst + 8) = p1;
    }
}

// s[b,c,o] += sum_k w(b,k,c) * u_hat[b,k,c,o]. Per block: 4 c (one per wave),
// 32 k accumulated in registers, then 16 atomicAdds per lane.
template <bool UNIFORM>
__global__ __launch_bounds__(256) void k_sacc(const uint16_t* __restrict__ uh,
                                              const float* __restrict__ cij,  // [k][c][b]
                                              float* __restrict__ s) {        // [b][c][o]
    const int lane = threadIdx.x & 63;
    const int wave = threadIdx.x >> 6;
    const int m = lane & 15;
    const int q = lane >> 4;
    const int c = (blockIdx.x & 15) * 4 + wave;
    const int k0 = (blockIdx.x >> 4) * 32;

    float acc[16];
#pragma unroll
    for (int i = 0; i < 16; ++i) acc[i] = 0.f;

    for (int kl = 0; kl < 32; ++kl) {
        const int k = k0 + kl;
        const uint16_t* up = uh + ((size_t)(k * Cc + c) * 64 + lane) * 16;
        uint4 q0 = *(const uint4*)up;
        uint4 q1 = *(const uint4*)(up + 8);
        float w0, w1;
        if (UNIFORM) {
            w0 = w1 = 1.0f / 64.0f;   // softmax of zeros
        } else {
            const float* cp = cij + (size_t)(k * Cc + c) * Bb + m;
            w0 = cp[0];    // b = m
            w1 = cp[16];   // b = 16+m
        }
        acc[0]  += w0 * bflo(q0.x);  acc[1]  += w0 * bfhi(q0.x);
        acc[2]  += w0 * bflo(q0.y);  acc[3]  += w0 * bfhi(q0.y);
        acc[4]  += w1 * bflo(q0.z);  acc[5]  += w1 * bfhi(q0.z);
        acc[6]  += w1 * bflo(q0.w);  acc[7]  += w1 * bfhi(q0.w);
        acc[8]  += w0 * bflo(q1.x);  acc[9]  += w0 * bfhi(q1.x);
        acc[10] += w0 * bflo(q1.y);  acc[11] += w0 * bfhi(q1.y);
        acc[12] += w1 * bflo(q1.z);  acc[13] += w1 * bfhi(q1.z);
        acc[14] += w1 * bflo(q1.w);  acc[15] += w1 * bfhi(q1.w);
    }
#pragma unroll
    for (int t = 0; t < 4; ++t) {
#pragma unroll
        for (int r = 0; r < 4; ++r) {
            const int b = (t & 1) * 16 + m;
            const int o = (t >> 1) * 16 + q * 4 + r;
            atomicAdd(&s[(size_t)(b * Cc + c) * Oo + o], acc[t * 4 + r]);
        }
    }
}

// Agreement + b update + softmax over c. Per block: 4 k's, all c.
// FIRST: b_new = agreement (b_prev==0), write b_new to bbuf, c1 -> cbuf.
// !FIRST: b_new = bbuf + agreement, c2 -> cbuf AND out [b][k][c].
template <bool FIRST>
__global__ __launch_bounds__(256) void k_route(const uint16_t* __restrict__ uh,
                                               const float* __restrict__ v,     // [b][c][o]
                                               float* __restrict__ bbuf,        // [k][b][c]
                                               float* __restrict__ cbuf,        // [k][c][b]
                                               float* __restrict__ outc) {      // [b][k][c]
    __shared__ float agr[4 * 64 * 32];
    const int tid = threadIdx.x;
    const int lane = tid & 63;
    const int wave = tid >> 6;
    const int m = lane & 15;
    const int q = lane >> 4;
    const int k0 = blockIdx.x * 4;

    for (int cc = 0; cc < 16; ++cc) {
        const int c = wave * 16 + cc;
        f32x4 vv[4];
#pragma unroll
        for (int t = 0; t < 4; ++t) {
            const int b = (t & 1) * 16 + m;
            const int o = (t >> 1) * 16 + q * 4;
            vv[t] = *(const f32x4*)&v[(size_t)(b * Cc + c) * Oo + o];
        }
#pragma unroll
        for (int kl = 0; kl < 4; ++kl) {
            const int k = k0 + kl;
            const uint16_t* up = uh + ((size_t)(k * Cc + c) * 64 + lane) * 16;
            uint4 q0 = *(const uint4*)up;
            uint4 q1 = *(const uint4*)(up + 8);
            // partial dots over this lane's 8 o's, for its two b values
            float p0 = bflo(q0.x) * vv[0].x + bfhi(q0.x) * vv[0].y
                     + bflo(q0.y) * vv[0].z + bfhi(q0.y) * vv[0].w
                     + bflo(q1.x) * vv[2].x + bfhi(q1.x) * vv[2].y
                     + bflo(q1.y) * vv[2].z + bfhi(q1.y) * vv[2].w;
            float p1 = bflo(q0.z) * vv[1].x + bfhi(q0.z) * vv[1].y
                     + bflo(q0.w) * vv[1].z + bfhi(q0.w) * vv[1].w
                     + bflo(q1.z) * vv[3].x + bfhi(q1.z) * vv[3].y
                     + bflo(q1.w) * vv[3].z + bfhi(q1.w) * vv[3].w;
            // reduce across the 4 quads (lanes l, l^16, l^32, l^48 share b)
            p0 += __shfl_xor(p0, 16);
            p0 += __shfl_xor(p0, 32);
            p1 += __shfl_xor(p1, 16);
            p1 += __shfl_xor(p1, 32);
            if (q == 0) {
                agr[(kl * 64 + c) * 32 + m] = p0;
                agr[(kl * 64 + c) * 32 + 16 + m] = p1;
            }
        }
    }
    __syncthreads();

    if (tid < 128) {
        const int kl = tid >> 5;
        const int b = tid & 31;
        const int k = k0 + kl;
        float row[64];
#pragma unroll
        for (int c = 0; c < 64; ++c) row[c] = agr[(kl * 64 + c) * 32 + b];
        if (FIRST) {
            float* bp = bbuf + (size_t)(k * Bb + b) * Cc;
#pragma unroll
            for (int c = 0; c < 64; ++c) bp[c] = row[c];
        } else {
            const float* bp = bbuf + (size_t)(k * Bb + b) * Cc;
#pragma unroll
            for (int c = 0; c < 64; ++c) row[c] += bp[c];
        }
        float mx = row[0];
#pragma unroll
        for (int c = 1; c < 64; ++c) mx = fmaxf(mx, row[c]);
        float sum = 0.f;
#pragma unroll
        for (int c = 0; c < 64; ++c) { row[c] = __expf(row[c] - mx); sum += row[c]; }
        const float inv = 1.f / sum;
#pragma unroll
        for (int c = 0; c < 64; ++c) row[c] *= inv;
        if (!FIRST) {
            float* op = outc + (size_t)(b * Kk + k) * Cc;
#pragma unroll
            for (int c = 0; c < 64; ++c) op[c] = row[c];
        }
#pragma unroll
        for (int c = 0; c < 64; ++c) agr[(kl * 64 + c) * 32 + b] = row[c];
    }
    __syncthreads();

    // write c_ij in [k][c][b] layout for k_sacc (coalesced)
    for (int idx = tid; idx < 4 * 64 * 32; idx += 256) {
        const int kl = idx >> 11;
        const int rem = idx & 2047;
        const int c = rem >> 5;
        const int b = rem & 31;
        cbuf[((size_t)(k0 + kl) * Cc + c) * Bb + b] = agr[idx];
    }
}

// v = squash(s) rowwise over O=32. 8 rows per 256-thread block.
__global__ __launch_bounds__(256) void k_squash(const float* __restrict__ s,
                                                float* __restrict__ v) {
    const int row = blockIdx.x * 8 + (threadIdx.x >> 5);
    const int o = threadIdx.x & 31;
    float val = s[(size_t)row * 32 + o];
    float sq = val * val;
    sq += __shfl_xor(sq, 1);
    sq += __shfl_xor(sq, 2);
    sq += __shfl_xor(sq, 4);
    sq += __shfl_xor(sq, 8);
    sq += __shfl_xor(sq, 16);
    const float coef = sq / ((1.f + sq) * sqrtf(sq + 1e-8f));
    v[(size_t)row * 32 + o] = val * coef;
}

extern "C" void kernel_launch(void* const* d_in, const int* in_sizes, int n_in,
                              void* d_out, int out_size, void* d_ws, size_t ws_size,
                              hipStream_t stream) {
    (void)in_sizes; (void)n_in; (void)out_size;
    const float* x = (const float*)d_in[0];
    const float* W = (const float*)d_in[1];
    float* out_v = (float*)d_out;                  // [B][C][O] = 65536 floats
    float* out_c = out_v + Bb * Cc * Oo;           // [B][K][C] = 2097152 floats

    char* ws = (char*)d_ws;
    const size_t UH_BYTES = (size_t)Kk * Cc * 1024 * 2;   // 128 MB bf16 u_hat
    const size_t BB_BYTES = (size_t)Kk * Bb * Cc * 4;     // 8 MB
    const size_t SV = (size_t)Bb * Cc * Oo;               // 65536 floats

    uint16_t* uh = (uint16_t*)ws;
    float* bbuf = (float*)(ws + UH_BYTES);
    float* cbuf = (float*)(ws + UH_BYTES + BB_BYTES);
    float* s0 = (float*)(ws + UH_BYTES + 2 * BB_BYTES);
    float* s1 = s0 + SV;
    float* s2 = s1 + SV;
    float* v0 = s2 + SV;
    float* v1 = v0 + SV;
    const size_t NEED = UH_BYTES + 2 * BB_BYTES + 5 * SV * 4;  // ~145.3 MB
    if (ws_size < NEED) return;  // ws too small for this plan; fail visibly

    hipMemsetAsync(s0, 0, 3 * SV * 4, stream);

    k_uhat<<<Kk, 256, 0, stream>>>(x, W, uh);
    // iter 0: c = 1/64 uniform
    k_sacc<true><<<512, 256, 0, stream>>>(uh, nullptr, s0);
    k_squash<<<256, 256, 0, stream>>>(s0, v0);
    // iter 0 agreement -> b1; iter 1 softmax -> c1
    k_route<true><<<256, 256, 0, stream>>>(uh, v0, bbuf, cbuf, nullptr);
    k_sacc<false><<<512, 256, 0, stream>>>(uh, cbuf, s1);
    k_squash<<<256, 256, 0, stream>>>(s1, v1);
    // iter 1 agreement -> b2; iter 2 softmax -> c2 (final output)
    k_route<false><<<256, 256, 0, stream>>>(uh, v1, bbuf, cbuf, out_c);
    k_sacc<false><<<512, 256, 0, stream>>>(uh, cbuf, s2);
    k_squash<<<256, 256, 0, stream>>>(s2, out_v);
}

// Round 2
// 518.999 us; speedup vs baseline: 1.1530x; 1.1530x over previous
//
#include <hip/hip_runtime.h>
#include <stdint.h>

// B=32 batch, K=1024 capsules, C=64 classes, O=32 out dim, I=32 in dim, 3 routing iters.
#define Bb 32
#define Kk 1024
#define Cc 64
#define Oo 32
#define Ii 32

typedef __attribute__((ext_vector_type(8))) short bf16x8;
typedef __attribute__((ext_vector_type(4))) float f32x4;

__device__ __forceinline__ short f2bf(float f) {
    uint32_t u = __builtin_bit_cast(uint32_t, f);
    u += 0x7fffu + ((u >> 16) & 1u);   // RNE (inputs are finite)
    return (short)(u >> 16);
}
__device__ __forceinline__ float bflo(uint32_t u) { return __builtin_bit_cast(float, u << 16); }
__device__ __forceinline__ float bfhi(uint32_t u) { return __builtin_bit_cast(float, u & 0xffff0000u); }
__device__ __forceinline__ uint32_t pk2(float a, float b) {
    return (uint32_t)(uint16_t)f2bf(a) | ((uint32_t)(uint16_t)f2bf(b) << 16);
}

// uh layout (bf16, stored as dwords): per (k,c) 512 dwords.
//   dword index = (k*64+c)*512 + half*256 + lane*4 + e,  half0 = frag elems 0..7 (d0,d1),
//   half1 = elems 8..15 (d2,d3). Elem i=t*4+r of lane (m=lane&15,q=lane>>4) is
//   u_hat[b=(t&1)*16+m][o=(t>>1)*16+q*4+r]  (mfma_f32_16x16x32 C/D map, m89-verified).
// All stores/loads: 16 B per lane, lane-contiguous -> fully coalesced.

__global__ __launch_bounds__(256) void k_uhat(const float* __restrict__ x,
                                              const float* __restrict__ W,
                                              uint32_t* __restrict__ uh) {
    const int k = blockIdx.x;
    const int lane = threadIdx.x & 63;
    const int wave = threadIdx.x >> 6;
    const int m = lane & 15;
    const int q = lane >> 4;

    // B operand: B[i][b_local] = x[b0+b_local, k, i]; lane holds 8 consecutive i.
    bf16x8 bfrag[2];
#pragma unroll
    for (int nb = 0; nb < 2; ++nb) {
        const float* xp = x + (size_t)((nb * 16 + m) * Kk + k) * Ii + q * 8;
        f32x4 a = *(const f32x4*)xp;
        f32x4 b = *(const f32x4*)(xp + 4);
        bf16x8 t;
        t[0] = f2bf(a.x); t[1] = f2bf(a.y); t[2] = f2bf(a.z); t[3] = f2bf(a.w);
        t[4] = f2bf(b.x); t[5] = f2bf(b.y); t[6] = f2bf(b.z); t[7] = f2bf(b.w);
        bfrag[nb] = t;
    }

    for (int cc = 0; cc < 16; ++cc) {
        const int c = wave * 16 + cc;
        // A operand: A[o_local][i] = W[k,c,o0+o_local,i]; read-once -> nontemporal
        bf16x8 afrag[2];
#pragma unroll
        for (int mo = 0; mo < 2; ++mo) {
            const float* wp = W + (size_t)((k * Cc + c) * Oo + mo * 16 + m) * Ii + q * 8;
            f32x4 a = __builtin_nontemporal_load((const f32x4*)wp);
            f32x4 b = __builtin_nontemporal_load((const f32x4*)(wp + 4));
            bf16x8 t;
            t[0] = f2bf(a.x); t[1] = f2bf(a.y); t[2] = f2bf(a.z); t[3] = f2bf(a.w);
            t[4] = f2bf(b.x); t[5] = f2bf(b.y); t[6] = f2bf(b.z); t[7] = f2bf(b.w);
            afrag[mo] = t;
        }
        const f32x4 z = {0.f, 0.f, 0.f, 0.f};
        f32x4 d0 = __builtin_amdgcn_mfma_f32_16x16x32_bf16(afrag[0], bfrag[0], z, 0, 0, 0);
        f32x4 d1 = __builtin_amdgcn_mfma_f32_16x16x32_bf16(afrag[0], bfrag[1], z, 0, 0, 0);
        f32x4 d2 = __builtin_amdgcn_mfma_f32_16x16x32_bf16(afrag[1], bfrag[0], z, 0, 0, 0);
        f32x4 d3 = __builtin_amdgcn_mfma_f32_16x16x32_bf16(afrag[1], bfrag[1], z, 0, 0, 0);

        uint4 p0, p1;
        p0.x = pk2(d0.x, d0.y); p0.y = pk2(d0.z, d0.w);
        p0.z = pk2(d1.x, d1.y); p0.w = pk2(d1.z, d1.w);
        p1.x = pk2(d2.x, d2.y); p1.y = pk2(d2.z, d2.w);
        p1.z = pk2(d3.x, d3.y); p1.w = pk2(d3.z, d3.w);
        uint32_t* dst = uh + (size_t)(k * Cc + c) * 512 + lane * 4;
        *(uint4*)dst = p0;              // lane-contiguous 16 B, coalesced
        *(uint4*)(dst + 256) = p1;
    }
}

// Partial s: part[chunk][c][t(4)][lane(64)][r(4)] f32. NO atomics.
template <bool UNIFORM>
__global__ __launch_bounds__(256) void k_sacc(const uint32_t* __restrict__ uh,
                                              const float* __restrict__ cij,  // [k][c][b]
                                              float* __restrict__ part) {
    const int lane = threadIdx.x & 63;
    const int wave = threadIdx.x >> 6;
    const int m = lane & 15;
    const int c = (blockIdx.x & 15) * 4 + wave;
    const int chunk = blockIdx.x >> 4;
    const int k0 = chunk * 32;

    float acc[16];
#pragma unroll
    for (int i = 0; i < 16; ++i) acc[i] = 0.f;

    for (int kl = 0; kl < 32; ++kl) {
        const int k = k0 + kl;
        const uint32_t* up = uh + (size_t)(k * Cc + c) * 512 + lane * 4;
        uint4 q0 = *(const uint4*)up;
        uint4 q1 = *(const uint4*)(up + 256);
        float w0, w1;
        if (UNIFORM) {
            w0 = w1 = 1.0f / 64.0f;
        } else {
            const float* cp = cij + (size_t)(k * Cc + c) * Bb + m;
            w0 = cp[0];    // b = m
            w1 = cp[16];   // b = 16+m
        }
        acc[0]  += w0 * bflo(q0.x);  acc[1]  += w0 * bfhi(q0.x);
        acc[2]  += w0 * bflo(q0.y);  acc[3]  += w0 * bfhi(q0.y);
        acc[4]  += w1 * bflo(q0.z);  acc[5]  += w1 * bfhi(q0.z);
        acc[6]  += w1 * bflo(q0.w);  acc[7]  += w1 * bfhi(q0.w);
        acc[8]  += w0 * bflo(q1.x);  acc[9]  += w0 * bfhi(q1.x);
        acc[10] += w0 * bflo(q1.y);  acc[11] += w0 * bfhi(q1.y);
        acc[12] += w1 * bflo(q1.z);  acc[13] += w1 * bfhi(q1.z);
        acc[14] += w1 * bflo(q1.w);  acc[15] += w1 * bfhi(q1.w);
    }
#pragma unroll
    for (int t = 0; t < 4; ++t) {
        f32x4 v = {acc[t * 4 + 0], acc[t * 4 + 1], acc[t * 4 + 2], acc[t * 4 + 3]};
        *(f32x4*)&part[(((size_t)(chunk * Cc + c) * 4 + t) * 64 + lane) * 4] = v;  // coalesced
    }
}

// Sum 32 chunk-partials + squash. vfrag[c][lane][16] in fragment layout.
// FINAL also writes out_v[b][c][o].
template <bool FINAL>
__global__ __launch_bounds__(256) void k_reduce(const float* __restrict__ part,
                                                float* __restrict__ vfrag,
                                                float* __restrict__ out_v) {
    __shared__ float red[4 * 64 * 17];   // +1 pad: conflict-free at stride 17
    const int c = blockIdx.x;
    const int tid = threadIdx.x;
    const int lane = tid & 63;
    const int cg = tid >> 6;

    float acc[16];
#pragma unroll
    for (int i = 0; i < 16; ++i) acc[i] = 0.f;
    for (int ch = cg * 8; ch < cg * 8 + 8; ++ch) {
        const f32x4* p = (const f32x4*)part + (size_t)(ch * Cc + c) * 4 * 64 + lane;
#pragma unroll
        for (int t = 0; t < 4; ++t) {
            f32x4 v = p[t * 64];
            acc[t * 4 + 0] += v.x; acc[t * 4 + 1] += v.y;
            acc[t * 4 + 2] += v.z; acc[t * 4 + 3] += v.w;
        }
    }
#pragma unroll
    for (int i = 0; i < 16; ++i) red[(cg * 64 + lane) * 17 + i] = acc[i];
    __syncthreads();

    if (tid < 64) {
        float a[16];
#pragma unroll
        for (int i = 0; i < 16; ++i)
            a[i] = red[tid * 17 + i] + red[(64 + tid) * 17 + i]
                 + red[(128 + tid) * 17 + i] + red[(192 + tid) * 17 + i];
        // squash per b-row: t even -> b=m, t odd -> b=16+m; o spans lane quads
        float sq0 = 0.f, sq1 = 0.f;
#pragma unroll
        for (int r = 0; r < 4; ++r) {
            sq0 += a[r] * a[r] + a[8 + r] * a[8 + r];       // t=0,2
            sq1 += a[4 + r] * a[4 + r] + a[12 + r] * a[12 + r]; // t=1,3
        }
        sq0 += __shfl_xor(sq0, 16); sq0 += __shfl_xor(sq0, 32);
        sq1 += __shfl_xor(sq1, 16); sq1 += __shfl_xor(sq1, 32);
        const float c0 = sq0 / ((1.f + sq0) * sqrtf(sq0 + 1e-8f));
        const float c1 = sq1 / ((1.f + sq1) * sqrtf(sq1 + 1e-8f));
#pragma unroll
        for (int r = 0; r < 4; ++r) {
            a[r] *= c0; a[8 + r] *= c0;
            a[4 + r] *= c1; a[12 + r] *= c1;
        }
        float* vp = vfrag + ((size_t)c * 64 + tid) * 16;
#pragma unroll
        for (int t = 0; t < 4; ++t) {
            f32x4 v = {a[t * 4 + 0], a[t * 4 + 1], a[t * 4 + 2], a[t * 4 + 3]};
            *(f32x4*)(vp + t * 4) = v;
        }
        if (FINAL) {
            const int m = tid & 15, q = tid >> 4;
#pragma unroll
            for (int t = 0; t < 4; ++t)
#pragma unroll
                for (int r = 0; r < 4; ++r) {
                    const int b = (t & 1) * 16 + m;
                    const int o = (t >> 1) * 16 + q * 4 + r;
                    out_v[((size_t)b * Cc + c) * Oo + o] = a[t * 4 + r];
                }
        }
    }
}

// Agreement + b update + softmax over c. Per block: 4 k's, all c.
template <bool FIRST>
__global__ __launch_bounds__(256) void k_route(const uint32_t* __restrict__ uh,
                                               const float* __restrict__ vfrag,  // [c][lane][16]
                                               float* __restrict__ bbuf,         // [k][b][c]
                                               float* __restrict__ cbuf,         // [k][c][b]
                                               float* __restrict__ outc) {       // [b][k][c]
    __shared__ float agr[4 * 64 * 32];
    const int tid = threadIdx.x;
    const int lane = tid & 63;
    const int wave = tid >> 6;
    const int m = lane & 15;
    const int q = lane >> 4;
    const int k0 = blockIdx.x * 4;

    for (int cc = 0; cc < 16; ++cc) {
        const int c = wave * 16 + cc;
        const float* vp = vfrag + ((size_t)c * 64 + lane) * 16;  // this lane's own fragment
        f32x4 vv[4];
#pragma unroll
        for (int t = 0; t < 4; ++t) vv[t] = *(const f32x4*)(vp + t * 4);
#pragma unroll
        for (int kl = 0; kl < 4; ++kl) {
            const int k = k0 + kl;
            const uint32_t* up = uh + (size_t)(k * Cc + c) * 512 + lane * 4;
            uint4 q0 = *(const uint4*)up;
            uint4 q1 = *(const uint4*)(up + 256);
            float p0 = bflo(q0.x) * vv[0].x + bfhi(q0.x) * vv[0].y
                     + bflo(q0.y) * vv[0].z + bfhi(q0.y) * vv[0].w
                     + bflo(q1.x) * vv[2].x + bfhi(q1.x) * vv[2].y
                     + bflo(q1.y) * vv[2].z + bfhi(q1.y) * vv[2].w;
            float p1 = bflo(q0.z) * vv[1].x + bfhi(q0.z) * vv[1].y
                     + bflo(q0.w) * vv[1].z + bfhi(q0.w) * vv[1].w
                     + bflo(q1.z) * vv[3].x + bfhi(q1.z) * vv[3].y
                     + bflo(q1.w) * vv[3].z + bfhi(q1.w) * vv[3].w;
            p0 += __shfl_xor(p0, 16);
            p0 += __shfl_xor(p0, 32);
            p1 += __shfl_xor(p1, 16);
            p1 += __shfl_xor(p1, 32);
            if (q == 0) {
                agr[(kl * 64 + c) * 32 + m] = p0;
                agr[(kl * 64 + c) * 32 + 16 + m] = p1;
            }
        }
    }
    __syncthreads();

    if (tid < 128) {
        const int kl = tid >> 5;
        const int b = tid & 31;
        const int k = k0 + kl;
        float row[64];
#pragma unroll
        for (int c = 0; c < 64; ++c) row[c] = agr[(kl * 64 + c) * 32 + b];
        if (FIRST) {
            float* bp = bbuf + (size_t)(k * Bb + b) * Cc;
#pragma unroll
            for (int c = 0; c < 64; ++c) bp[c] = row[c];
        } else {
            const float* bp = bbuf + (size_t)(k * Bb + b) * Cc;
#pragma unroll
            for (int c = 0; c < 64; ++c) row[c] += bp[c];
        }
        float mx = row[0];
#pragma unroll
        for (int c = 1; c < 64; ++c) mx = fmaxf(mx, row[c]);
        float sum = 0.f;
#pragma unroll
        for (int c = 0; c < 64; ++c) { row[c] = __expf(row[c] - mx); sum += row[c]; }
        const float inv = 1.f / sum;
#pragma unroll
        for (int c = 0; c < 64; ++c) row[c] *= inv;
        if (!FIRST) {
            float* op = outc + (size_t)(b * Kk + k) * Cc;
#pragma unroll
            for (int c = 0; c < 64; ++c) op[c] = row[c];
        }
#pragma unroll
        for (int c = 0; c < 64; ++c) agr[(kl * 64 + c) * 32 + b] = row[c];
    }
    __syncthreads();

    for (int idx = tid; idx < 4 * 64 * 32; idx += 256) {
        const int kl = idx >> 11;
        const int rem = idx & 2047;
        const int c = rem >> 5;
        const int b = rem & 31;
        cbuf[((size_t)(k0 + kl) * Cc + c) * Bb + b] = agr[idx];
    }
}

extern "C" void kernel_launch(void* const* d_in, const int* in_sizes, int n_in,
                              void* d_out, int out_size, void* d_ws, size_t ws_size,
                              hipStream_t stream) {
    (void)in_sizes; (void)n_in; (void)out_size;
    const float* x = (const float*)d_in[0];
    const float* W = (const float*)d_in[1];
    float* out_v = (float*)d_out;                  // [B][C][O]
    float* out_c = out_v + Bb * Cc * Oo;           // [B][K][C]

    char* ws = (char*)d_ws;
    const size_t UH_BYTES = (size_t)Kk * Cc * 512 * 4;        // 128 MiB
    const size_t PART_BYTES = (size_t)32 * Cc * 4 * 64 * 4 * 4; // 8 MiB
    const size_t BB_BYTES = (size_t)Kk * Bb * Cc * 4;         // 8 MiB
    const size_t VF_BYTES = (size_t)Cc * 64 * 16 * 4;         // 256 KiB

    uint32_t* uh = (uint32_t*)ws;
    float* part  = (float*)(ws + UH_BYTES);
    float* bbuf  = (float*)(ws + UH_BYTES + PART_BYTES);
    float* cbuf  = (float*)(ws + UH_BYTES + PART_BYTES + BB_BYTES);
    float* vfrag = (float*)(ws + UH_BYTES + PART_BYTES + 2 * BB_BYTES);
    const size_t NEED = UH_BYTES + PART_BYTES + 2 * BB_BYTES + VF_BYTES;
    if (ws_size < NEED) return;

    k_uhat<<<Kk, 256, 0, stream>>>(x, W, uh);
    // iter 0: uniform c = 1/64
    k_sacc<true><<<512, 256, 0, stream>>>(uh, nullptr, part);
    k_reduce<false><<<Cc, 256, 0, stream>>>(part, vfrag, nullptr);
    k_route<true><<<256, 256, 0, stream>>>(uh, vfrag, bbuf, cbuf, nullptr);
    // iter 1
    k_sacc<false><<<512, 256, 0, stream>>>(uh, cbuf, part);
    k_reduce<false><<<Cc, 256, 0, stream>>>(part, vfrag, nullptr);
    k_route<false><<<256, 256, 0, stream>>>(uh, vfrag, bbuf, cbuf, out_c);
    // iter 2
    k_sacc<false><<<512, 256, 0, stream>>>(uh, cbuf, part);
    k_reduce<true><<<Cc, 256, 0, stream>>>(part, vfrag, out_v);
}